// Round 6
// baseline (156.058 us; speedup 1.0000x reference)
//
#include <hip/hip_runtime.h>

#define HH 256
#define WW 256
#define NPIX (2 * HH * WW)   // 131072 (B=2)
#define NC 48
#define OT 32         // output tile (32x32 per block)
#define PT 38         // phi tile = OT+6
#define PSTR 44       // phi LDS row stride (16B aligned)
#define UT 44         // u tile = OT+12
#define USTR 52       // u LDS row stride (16B aligned)
#define NB 31
#define TM 385        // phi-table points per channel, x in [-1.5,1.5], h=3/384

__device__ __forceinline__ float lerp_tab(const float* __restrict__ t, float x) {
    float s = fminf(fmaxf(fmaf(x, 128.f, 192.f), 0.f), 383.999f);
    float fj = floorf(s);
    int i = (int)fj;
    return fmaf(s - fj, t[i + 1] - t[i], t[i]);
}

// Fused: per-block phi tables -> conv1(7x7, 2ch/pass, 8px items) -> table-lerp
// RBF -> conv2(flipped 7x7, 2ch/pass). Round-4 structure (62 us) + balanced
// single-batch conv1 + 4 blocks/CU (NG=8 groups of CG=6 channels).
// All accumulators NAMED SCALARS (round 3: arrays -> 700 MB scratch spill).
// Round 5 lesson: 4ch/pass + full unroll ballooned VALU 34->47 us — keep
// 2ch/pass and non-unrolled dy loops.
__global__ __launch_bounds__(256, 4)
void tnrd_main(const float* __restrict__ u,
               const float* __restrict__ wf,   // filters [48][49]
               const float* __restrict__ wr,   // rbf weights [48][31]
               float* __restrict__ part,
               int ng, int cg)
{
    __shared__ __align__(16) float u_s[UT * USTR];          //  9152 B
    __shared__ __align__(16) float phi_s[2][PT * PSTR];     // 13376 B
    __shared__ __align__(16) float tabs[8][TM + 1];         // 12352 B (<=8 ch)

    const int tid = threadIdx.x;
    const int bx = blockIdx.x, by = blockIdx.y;
    const int b = blockIdx.z / ng, g = blockIdx.z % ng;
    const int c0 = g * cg;

    // ---- stage u tile (6-halo, zero-padded incl. stride pad) ----
    const int uy0 = by * OT - 6, ux0 = bx * OT - 6;
    const float* ub = u + b * (HH * WW);
    for (int i = tid; i < UT * USTR; i += 256) {
        int r = i / USTR, c = i - r * USTR;
        int gy = uy0 + r, gx = ux0 + c;
        float v = 0.f;
        if (c < UT && (unsigned)gy < HH && (unsigned)gx < WW)
            v = ub[gy * WW + gx];
        u_s[i] = v;
    }

    // ---- build this group's phi tables in LDS (386 pts incl. lerp guard) ----
    for (int ch = 0; ch < cg; ++ch) {
        const float* rc = wr + (c0 + ch) * NB;   // block-uniform -> s_load
        for (int j = tid; j < TM + 1; j += 256) {
            float x = fmaf((float)j, 3.0f / 384.0f, -1.5f);
            float s = 0.f;
            #pragma unroll
            for (int k = 0; k < NB; ++k) {
                float mu = -1.f + (float)k * (1.f / 15.f);
                float d = x - mu;
                s = fmaf(rc[k], __expf(-50.f * d * d), s);
            }
            tabs[ch][j] = s;
        }
    }
    __syncthreads();

    const int oy = tid >> 3;        // 0..31
    const int ox0 = (tid & 7) * 4;  // 0..28
    float o0 = 0.f, o1 = 0.f, o2 = 0.f, o3 = 0.f;
    const int py0 = by * OT - 3, px0 = bx * OT - 3;

    const int npass = cg >> 1;
    for (int pass = 0; pass < npass; ++pass) {   // 2 channels per pass
        const float* wA = wf + (c0 + 2 * pass) * 49;   // block-uniform s_load
        const float* wB = wA + 49;
        const float* tA = tabs[2 * pass];
        const float* tB = tabs[2 * pass + 1];

        // ---- conv1 + lerp: 190 items = 38 rows x 5 octets, single batch ----
        if (tid < PT * 5) {
            const int pr = tid / 5, pc = (tid - pr * 5) * 8;
            float a0 = 0.f, a1 = 0.f, a2 = 0.f, a3 = 0.f;
            float a4 = 0.f, a5 = 0.f, a6 = 0.f, a7 = 0.f;
            float b0 = 0.f, b1 = 0.f, b2 = 0.f, b3 = 0.f;
            float b4 = 0.f, b5 = 0.f, b6 = 0.f, b7 = 0.f;
            const float* base = &u_s[pr * USTR + pc];
            for (int dy = 0; dy < 7; ++dy) {     // not unrolled (round 5 lesson)
                const float* row = base + dy * USTR;
                float sv[20];
                #pragma unroll
                for (int j = 0; j < 20; ++j) sv[j] = row[j];  // 5x ds_read_b128
                const float* wa = wA + dy * 7;
                const float* wb = wB + dy * 7;
                #pragma unroll
                for (int dx = 0; dx < 7; ++dx) {
                    const float fa = wa[dx], fb = wb[dx];
                    a0 = fmaf(sv[dx],     fa, a0);
                    a1 = fmaf(sv[dx + 1], fa, a1);
                    a2 = fmaf(sv[dx + 2], fa, a2);
                    a3 = fmaf(sv[dx + 3], fa, a3);
                    a4 = fmaf(sv[dx + 4], fa, a4);
                    a5 = fmaf(sv[dx + 5], fa, a5);
                    a6 = fmaf(sv[dx + 6], fa, a6);
                    a7 = fmaf(sv[dx + 7], fa, a7);
                    b0 = fmaf(sv[dx],     fb, b0);
                    b1 = fmaf(sv[dx + 1], fb, b1);
                    b2 = fmaf(sv[dx + 2], fb, b2);
                    b3 = fmaf(sv[dx + 3], fb, b3);
                    b4 = fmaf(sv[dx + 4], fb, b4);
                    b5 = fmaf(sv[dx + 5], fb, b5);
                    b6 = fmaf(sv[dx + 6], fb, b6);
                    b7 = fmaf(sv[dx + 7], fb, b7);
                }
            }
            // ---- table lerp; phi = 0 outside image (conv2 zero-pad) ----
            const int gy = py0 + pr;
            const bool rowok = (unsigned)gy < HH;
            const float av[8] = {a0, a1, a2, a3, a4, a5, a6, a7};
            const float bv[8] = {b0, b1, b2, b3, b4, b5, b6, b7};
            float pa[8], pb[8];
            #pragma unroll
            for (int j = 0; j < 8; ++j) {
                const bool ok = rowok && (unsigned)(px0 + pc + j) < WW;
                pa[j] = ok ? lerp_tab(tA, av[j]) : 0.f;
                pb[j] = ok ? lerp_tab(tB, bv[j]) : 0.f;
            }
            const int po = pr * PSTR + pc;       // 16B-aligned (PSTR=44, pc%8=0)
            *(float4*)&phi_s[0][po]     = make_float4(pa[0], pa[1], pa[2], pa[3]);
            *(float4*)&phi_s[0][po + 4] = make_float4(pa[4], pa[5], pa[6], pa[7]);
            *(float4*)&phi_s[1][po]     = make_float4(pb[0], pb[1], pb[2], pb[3]);
            *(float4*)&phi_s[1][po + 4] = make_float4(pb[4], pb[5], pb[6], pb[7]);
        }
        __syncthreads();

        // ---- conv2 accumulate both channels, spatially-flipped weights ----
        const int co = oy * PSTR + ox0;
        for (int dy = 0; dy < 7; ++dy) {         // not unrolled (round 5 lesson)
            const float* rA = &phi_s[0][co + dy * PSTR];
            const float* rB = &phi_s[1][co + dy * PSTR];
            float sa[10], sb[10];
            #pragma unroll
            for (int j = 0; j < 10; ++j) sa[j] = rA[j];
            #pragma unroll
            for (int j = 0; j < 10; ++j) sb[j] = rB[j];
            #pragma unroll
            for (int dx = 0; dx < 7; ++dx) {
                const float fa = wA[(6 - dy) * 7 + (6 - dx)];
                const float fb = wB[(6 - dy) * 7 + (6 - dx)];
                o0 = fmaf(sa[dx],     fa, o0);
                o1 = fmaf(sa[dx + 1], fa, o1);
                o2 = fmaf(sa[dx + 2], fa, o2);
                o3 = fmaf(sa[dx + 3], fa, o3);
                o0 = fmaf(sb[dx],     fb, o0);
                o1 = fmaf(sb[dx + 1], fb, o1);
                o2 = fmaf(sb[dx + 2], fb, o2);
                o3 = fmaf(sb[dx + 3], fb, o3);
            }
        }
        if (pass != npass - 1) __syncthreads();  // protect phi_s for next pass
    }

    const int gy = by * OT + oy, gx = bx * OT + ox0;
    float4 v4 = make_float4(o0, o1, o2, o3);
    *reinterpret_cast<float4*>(part + (size_t)g * NPIX + b * (HH * WW)
                               + gy * WW + gx) = v4;
}

__global__ __launch_bounds__(256)
void combine_kernel(const float* __restrict__ u,
                    const float* __restrict__ f,
                    const float* __restrict__ lam,
                    const float* __restrict__ part,
                    float* __restrict__ out, int ng)
{
    int i = blockIdx.x * 256 + threadIdx.x;  // 512 blocks -> NPIX
    float d = 0.f;
    for (int g = 0; g < ng; ++g) d += part[g * NPIX + i];
    float lv = lam[0];
    float uv = u[i];
    float fv = f[i];
    out[i] = uv - d - lv * (uv - fv);
}

extern "C" void kernel_launch(void* const* d_in, const int* in_sizes, int n_in,
                              void* d_out, int out_size, void* d_ws, size_t ws_size,
                              hipStream_t stream) {
    const float* u    = (const float*)d_in[0];
    const float* f    = (const float*)d_in[1];
    const float* filt = (const float*)d_in[2];
    const float* rbfw = (const float*)d_in[3];
    const float* lam  = (const float*)d_in[4];
    float* out = (float*)d_out;
    float* part = (float*)d_ws;   // ng * 131072 f32 partial sums

    // NG=8 -> grid 1024 = 4 blocks/CU (needs 4.2 MB ws); else NG=6 (3.1 MB).
    const int ng = (ws_size >= (size_t)8 * NPIX * 4) ? 8 : 6;
    const int cg = NC / ng;

    tnrd_main<<<dim3(8, 8, 2 * ng), 256, 0, stream>>>(u, filt, rbfw, part, ng, cg);
    combine_kernel<<<512, 256, 0, stream>>>(u, f, lam, part, out, ng);
}

// Round 7
// 126.687 us; speedup vs baseline: 1.2318x; 1.2318x over previous
//
#include <hip/hip_runtime.h>

#define HH 256
#define WW 256
#define NPIX (2 * HH * WW)   // 131072 (B=2)
#define NC 48
#define OT 32         // output tile (32x32 per block)
#define PT 38         // phi tile = OT+6
#define PSTR 44       // phi LDS row stride (16B aligned)
#define UT 44         // u tile = OT+12
#define USTR 52       // u LDS row stride (16B aligned)
#define NB 31
#define TM 385        // phi-table points per channel, x in [-1.5,1.5], h=3/384

// Fused: per-block phi tables -> conv1(7x7, 2ch/pass, 4px items x2 batches) ->
// table-lerp RBF -> conv2(flipped 7x7, 2ch/pass). This is the round-4 body
// (62 us, no spill) verbatim; only the channel grouping is templated.
// Hard-won constraints (do not violate):
//  - all per-lane accumulators NAMED SCALARS (r3: cv[2][8][4] -> 700 MB spill)
//  - 2 channels/pass, dy loops NOT unrolled (r5: 4ch+unroll -> VALU 34->47 us)
//  - 4-px items with sv[12] (r6: 8-px items/sv[20] -> 300 MB spill)
template <int CG_>
__global__ __launch_bounds__(256, 3)
void tnrd_main(const float* __restrict__ u,
               const float* __restrict__ wf,   // filters [48][49]
               const float* __restrict__ wr,   // rbf weights [48][31]
               float* __restrict__ part)
{
    __shared__ __align__(16) float u_s[UT * USTR];          //  9152 B
    __shared__ __align__(16) float phi_s[2][PT * PSTR];     // 13376 B
    __shared__ __align__(16) float tabs[CG_][TM + 1];       //  9264 B @ CG=6

    constexpr int NG_ = NC / CG_;
    const int tid = threadIdx.x;
    const int bx = blockIdx.x, by = blockIdx.y;
    const int b = blockIdx.z / NG_, g = blockIdx.z % NG_;
    const int c0 = g * CG_;

    // ---- stage u tile (6-halo, zero-padded incl. stride pad) ----
    const int uy0 = by * OT - 6, ux0 = bx * OT - 6;
    const float* ub = u + b * (HH * WW);
    for (int i = tid; i < UT * USTR; i += 256) {
        int r = i / USTR, c = i - r * USTR;
        int gy = uy0 + r, gx = ux0 + c;
        float v = 0.f;
        if (c < UT && (unsigned)gy < HH && (unsigned)gx < WW)
            v = ub[gy * WW + gx];
        u_s[i] = v;
    }

    // ---- build this group's phi tables in LDS (386 pts incl. lerp guard) ----
    #pragma unroll
    for (int ch = 0; ch < CG_; ++ch) {
        const float* rc = wr + (c0 + ch) * NB;   // block-uniform -> s_load
        for (int j = tid; j < TM + 1; j += 256) {
            float x = fmaf((float)j, 3.0f / 384.0f, -1.5f);
            float s = 0.f;
            #pragma unroll
            for (int k = 0; k < NB; ++k) {
                float mu = -1.f + (float)k * (1.f / 15.f);
                float d = x - mu;
                s = fmaf(rc[k], __expf(-50.f * d * d), s);
            }
            tabs[ch][j] = s;
        }
    }
    __syncthreads();

    const int oy = tid >> 3;        // 0..31
    const int ox0 = (tid & 7) * 4;  // 0..28
    float o0 = 0.f, o1 = 0.f, o2 = 0.f, o3 = 0.f;
    const int py0 = by * OT - 3, px0 = bx * OT - 3;

    constexpr int npass = CG_ / 2;
    for (int pass = 0; pass < npass; ++pass) {   // 2 channels per pass
        const float* wA = wf + (c0 + 2 * pass) * 49;   // block-uniform s_load
        const float* wB = wA + 49;

        // ---- conv1 + RBF lerp; 380 items = 38 rows x 10 quads, 2 batches ----
        for (int p = 0; p < 2; ++p) {
            const int gi = tid + p * 256;
            if (gi < PT * 10) {
                const int pr = gi / 10, pc = (gi - pr * 10) * 4;
                float a0 = 0.f, a1 = 0.f, a2 = 0.f, a3 = 0.f;   // ch A, 4 px
                float b0 = 0.f, b1 = 0.f, b2 = 0.f, b3 = 0.f;   // ch B, 4 px
                for (int dy = 0; dy < 7; ++dy) {
                    const float* row = &u_s[(pr + dy) * USTR + pc];
                    float sv[12];
                    #pragma unroll
                    for (int j = 0; j < 12; ++j) sv[j] = row[j]; // 3x ds_read_b128
                    const float* wa = wA + dy * 7;
                    const float* wb = wB + dy * 7;
                    #pragma unroll
                    for (int dx = 0; dx < 7; ++dx) {
                        float fa = wa[dx], fb = wb[dx];
                        a0 = fmaf(sv[dx],     fa, a0);
                        a1 = fmaf(sv[dx + 1], fa, a1);
                        a2 = fmaf(sv[dx + 2], fa, a2);
                        a3 = fmaf(sv[dx + 3], fa, a3);
                        b0 = fmaf(sv[dx],     fb, b0);
                        b1 = fmaf(sv[dx + 1], fb, b1);
                        b2 = fmaf(sv[dx + 2], fb, b2);
                        b3 = fmaf(sv[dx + 3], fb, b3);
                    }
                }
                // ---- table lerp; phi = 0 outside image (conv2 zero-pad) ----
                const int gy = py0 + pr;
                const bool rowok = (unsigned)gy < HH;
                float av[4] = {a0, a1, a2, a3};
                float bv[4] = {b0, b1, b2, b3};
                float pha[4], phb[4];
                #pragma unroll
                for (int j = 0; j < 4; ++j) {
                    bool ok = rowok && (unsigned)(px0 + pc + j) < WW;
                    const float* tA = tabs[2 * pass];
                    const float* tB = tabs[2 * pass + 1];
                    float ta = fminf(fmaxf(fmaf(av[j], 128.f, 192.f), 0.f), 383.999f);
                    float fja = floorf(ta);
                    int ia = (int)fja;
                    float va = fmaf(ta - fja, tA[ia + 1] - tA[ia], tA[ia]);
                    float tb = fminf(fmaxf(fmaf(bv[j], 128.f, 192.f), 0.f), 383.999f);
                    float fjb = floorf(tb);
                    int ib = (int)fjb;
                    float vb = fmaf(tb - fjb, tB[ib + 1] - tB[ib], tB[ib]);
                    pha[j] = ok ? va : 0.f;
                    phb[j] = ok ? vb : 0.f;
                }
                float* dA = &phi_s[0][pr * PSTR + pc];
                float* dB = &phi_s[1][pr * PSTR + pc];
                #pragma unroll
                for (int j = 0; j < 4; ++j) dA[j] = pha[j];  // ds_write_b128
                #pragma unroll
                for (int j = 0; j < 4; ++j) dB[j] = phb[j];  // ds_write_b128
            }
        }
        __syncthreads();

        // ---- conv2 accumulate both channels, spatially-flipped weights ----
        for (int dy = 0; dy < 7; ++dy) {
            const float* rA = &phi_s[0][(oy + dy) * PSTR + ox0];
            const float* rB = &phi_s[1][(oy + dy) * PSTR + ox0];
            float sa[10], sb[10];
            #pragma unroll
            for (int j = 0; j < 10; ++j) sa[j] = rA[j];
            #pragma unroll
            for (int j = 0; j < 10; ++j) sb[j] = rB[j];
            #pragma unroll
            for (int dx = 0; dx < 7; ++dx) {
                float fa = wA[(6 - dy) * 7 + (6 - dx)];
                float fb = wB[(6 - dy) * 7 + (6 - dx)];
                o0 = fmaf(sa[dx],     fa, o0);
                o1 = fmaf(sa[dx + 1], fa, o1);
                o2 = fmaf(sa[dx + 2], fa, o2);
                o3 = fmaf(sa[dx + 3], fa, o3);
                o0 = fmaf(sb[dx],     fb, o0);
                o1 = fmaf(sb[dx + 1], fb, o1);
                o2 = fmaf(sb[dx + 2], fb, o2);
                o3 = fmaf(sb[dx + 3], fb, o3);
            }
        }
        if (pass != npass - 1) __syncthreads();  // protect phi_s for next pass
    }

    const int gy = by * OT + oy, gx = bx * OT + ox0;
    float4 v4 = make_float4(o0, o1, o2, o3);
    *reinterpret_cast<float4*>(part + (size_t)g * NPIX + b * (HH * WW)
                               + gy * WW + gx) = v4;
}

__global__ __launch_bounds__(256)
void combine_kernel(const float* __restrict__ u,
                    const float* __restrict__ f,
                    const float* __restrict__ lam,
                    const float* __restrict__ part,
                    float* __restrict__ out, int ng)
{
    int i = blockIdx.x * 256 + threadIdx.x;  // 512 blocks -> NPIX
    float d = 0.f;
    for (int g = 0; g < ng; ++g) d += part[g * NPIX + i];
    float lv = lam[0];
    float uv = u[i];
    float fv = f[i];
    out[i] = uv - d - lv * (uv - fv);
}

extern "C" void kernel_launch(void* const* d_in, const int* in_sizes, int n_in,
                              void* d_out, int out_size, void* d_ws, size_t ws_size,
                              hipStream_t stream) {
    const float* u    = (const float*)d_in[0];
    const float* f    = (const float*)d_in[1];
    const float* filt = (const float*)d_in[2];
    const float* rbfw = (const float*)d_in[3];
    const float* lam  = (const float*)d_in[4];
    float* out = (float*)d_out;
    float* part = (float*)d_ws;   // ng * 131072 f32 partial sums

    // NG=8 (CG=6): grid 1024 = 4 blocks/CU, needs 4 MB ws; fallback NG=6.
    if (ws_size >= (size_t)8 * NPIX * 4) {
        tnrd_main<6><<<dim3(8, 8, 16), 256, 0, stream>>>(u, filt, rbfw, part);
        combine_kernel<<<512, 256, 0, stream>>>(u, f, lam, part, out, 8);
    } else {
        tnrd_main<8><<<dim3(8, 8, 12), 256, 0, stream>>>(u, filt, rbfw, part);
        combine_kernel<<<512, 256, 0, stream>>>(u, f, lam, part, out, 6);
    }
}

// Round 8
// 114.790 us; speedup vs baseline: 1.3595x; 1.1036x over previous
//
#include <hip/hip_runtime.h>

#define HH 256
#define WW 256
#define NPIX (2 * HH * WW)   // 131072 (B=2)
#define NC 48
#define NB 31
#define NG 6          // channel groups
#define CG 8          // channels per group (NG*CG == NC)
#define OT 32         // output tile (32x32 per block)
#define PT 38         // phi tile = OT+6
#define PSTR 44       // phi LDS row stride (16B aligned)
#define UT 44         // u tile = OT+12
#define USTR 52       // u LDS row stride (16B aligned)
#define TM 385        // phi-table points per channel, x in [-1.5,1.5], h=3/384
#define TSTR 386      // table stride (incl. lerp guard entry)

// ---- Build the 48 phi tables once: tab[c][j], j=0..385 (386 incl. guard).
// 48 blocks; trivial cost. Lives in d_out scratch (overwritten by combine).
__global__ __launch_bounds__(256)
void tnrd_table(const float* __restrict__ wr, float* __restrict__ tab)
{
    const int ch = blockIdx.x;
    const float* rc = wr + ch * NB;
    for (int j = threadIdx.x; j < TSTR; j += 256) {
        float x = fmaf((float)j, 3.0f / 384.0f, -1.5f);
        float s = 0.f;
        #pragma unroll
        for (int k = 0; k < NB; ++k) {
            float mu = -1.f + (float)k * (1.f / 15.f);
            float d = x - mu;
            s = fmaf(rc[k], __expf(-50.f * d * d), s);
        }
        tab[ch * TSTR + j] = s;
    }
}

// Fused: conv1(7x7, 2ch/pass, 4px items x2 batches) -> table-lerp RBF ->
// conv2(flipped 7x7, 2ch/pass). Round-4 body (62 us, 64 VGPR, no spill)
// VERBATIM except the in-kernel table build is replaced by a global->LDS copy.
// Hard-won constraints (do not violate):
//  - all per-lane accumulators NAMED SCALARS (r3: cv[2][8][4] -> 700 MB spill)
//  - 2 channels/pass, dy loops NOT unrolled (r5: 4ch+unroll -> VALU 34->47 us)
//  - 4-px items with sv[12] (r6: 8-px items/sv[20] -> 300 MB spill)
//  - do not re-template/regroup channels (r7: CG=6 variant -> 84 VGPR + spill)
__global__ __launch_bounds__(256, 3)
void tnrd_main(const float* __restrict__ u,
               const float* __restrict__ wf,    // filters [48][49]
               const float* __restrict__ tab,   // phi tables [48][TSTR]
               float* __restrict__ part)
{
    __shared__ __align__(16) float u_s[UT * USTR];          //  9152 B
    __shared__ __align__(16) float phi_s[2][PT * PSTR];     // 13376 B
    __shared__ __align__(16) float tabs[CG][TSTR];          // 12352 B

    const int tid = threadIdx.x;
    const int bx = blockIdx.x, by = blockIdx.y;
    const int b = blockIdx.z / NG, g = blockIdx.z % NG;
    const int c0 = g * CG;

    // ---- stage u tile (6-halo, zero-padded incl. stride pad) ----
    const int uy0 = by * OT - 6, ux0 = bx * OT - 6;
    const float* ub = u + b * (HH * WW);
    for (int i = tid; i < UT * USTR; i += 256) {
        int r = i / USTR, c = i - r * USTR;
        int gy = uy0 + r, gx = ux0 + c;
        float v = 0.f;
        if (c < UT && (unsigned)gy < HH && (unsigned)gx < WW)
            v = ub[gy * WW + gx];
        u_s[i] = v;
    }

    // ---- stage this group's 8 tables: 3088 floats = 772 float4 (L2-hit) ----
    {
        const float4* src = (const float4*)(tab + c0 * TSTR);
        float4* dst = (float4*)&tabs[0][0];
        for (int i = tid; i < CG * TSTR / 4; i += 256) dst[i] = src[i];
    }
    __syncthreads();

    const int oy = tid >> 3;        // 0..31
    const int ox0 = (tid & 7) * 4;  // 0..28
    float o0 = 0.f, o1 = 0.f, o2 = 0.f, o3 = 0.f;
    const int py0 = by * OT - 3, px0 = bx * OT - 3;

    for (int pass = 0; pass < 4; ++pass) {       // 2 channels per pass
        const float* wA = wf + (c0 + 2 * pass) * 49;   // block-uniform s_load
        const float* wB = wA + 49;

        // ---- conv1 + RBF lerp; 380 items = 38 rows x 10 quads, 2 batches ----
        for (int p = 0; p < 2; ++p) {
            const int gi = tid + p * 256;
            if (gi < PT * 10) {
                const int pr = gi / 10, pc = (gi - pr * 10) * 4;
                float a0 = 0.f, a1 = 0.f, a2 = 0.f, a3 = 0.f;   // ch A, 4 px
                float b0 = 0.f, b1 = 0.f, b2 = 0.f, b3 = 0.f;   // ch B, 4 px
                for (int dy = 0; dy < 7; ++dy) {
                    const float* row = &u_s[(pr + dy) * USTR + pc];
                    float sv[12];
                    #pragma unroll
                    for (int j = 0; j < 12; ++j) sv[j] = row[j]; // 3x ds_read_b128
                    const float* wa = wA + dy * 7;
                    const float* wb = wB + dy * 7;
                    #pragma unroll
                    for (int dx = 0; dx < 7; ++dx) {
                        float fa = wa[dx], fb = wb[dx];
                        a0 = fmaf(sv[dx],     fa, a0);
                        a1 = fmaf(sv[dx + 1], fa, a1);
                        a2 = fmaf(sv[dx + 2], fa, a2);
                        a3 = fmaf(sv[dx + 3], fa, a3);
                        b0 = fmaf(sv[dx],     fb, b0);
                        b1 = fmaf(sv[dx + 1], fb, b1);
                        b2 = fmaf(sv[dx + 2], fb, b2);
                        b3 = fmaf(sv[dx + 3], fb, b3);
                    }
                }
                // ---- table lerp; phi = 0 outside image (conv2 zero-pad) ----
                const int gy = py0 + pr;
                const bool rowok = (unsigned)gy < HH;
                float av[4] = {a0, a1, a2, a3};
                float bv[4] = {b0, b1, b2, b3};
                float pha[4], phb[4];
                #pragma unroll
                for (int j = 0; j < 4; ++j) {
                    bool ok = rowok && (unsigned)(px0 + pc + j) < WW;
                    const float* tA = tabs[2 * pass];
                    const float* tB = tabs[2 * pass + 1];
                    float ta = fminf(fmaxf(fmaf(av[j], 128.f, 192.f), 0.f), 383.999f);
                    float fja = floorf(ta);
                    int ia = (int)fja;
                    float va = fmaf(ta - fja, tA[ia + 1] - tA[ia], tA[ia]);
                    float tb = fminf(fmaxf(fmaf(bv[j], 128.f, 192.f), 0.f), 383.999f);
                    float fjb = floorf(tb);
                    int ib = (int)fjb;
                    float vb = fmaf(tb - fjb, tB[ib + 1] - tB[ib], tB[ib]);
                    pha[j] = ok ? va : 0.f;
                    phb[j] = ok ? vb : 0.f;
                }
                float* dA = &phi_s[0][pr * PSTR + pc];
                float* dB = &phi_s[1][pr * PSTR + pc];
                #pragma unroll
                for (int j = 0; j < 4; ++j) dA[j] = pha[j];  // ds_write_b128
                #pragma unroll
                for (int j = 0; j < 4; ++j) dB[j] = phb[j];  // ds_write_b128
            }
        }
        __syncthreads();

        // ---- conv2 accumulate both channels, spatially-flipped weights ----
        for (int dy = 0; dy < 7; ++dy) {
            const float* rA = &phi_s[0][(oy + dy) * PSTR + ox0];
            const float* rB = &phi_s[1][(oy + dy) * PSTR + ox0];
            float sa[10], sb[10];
            #pragma unroll
            for (int j = 0; j < 10; ++j) sa[j] = rA[j];
            #pragma unroll
            for (int j = 0; j < 10; ++j) sb[j] = rB[j];
            #pragma unroll
            for (int dx = 0; dx < 7; ++dx) {
                float fa = wA[(6 - dy) * 7 + (6 - dx)];
                float fb = wB[(6 - dy) * 7 + (6 - dx)];
                o0 = fmaf(sa[dx],     fa, o0);
                o1 = fmaf(sa[dx + 1], fa, o1);
                o2 = fmaf(sa[dx + 2], fa, o2);
                o3 = fmaf(sa[dx + 3], fa, o3);
                o0 = fmaf(sb[dx],     fb, o0);
                o1 = fmaf(sb[dx + 1], fb, o1);
                o2 = fmaf(sb[dx + 2], fb, o2);
                o3 = fmaf(sb[dx + 3], fb, o3);
            }
        }
        if (pass != 3) __syncthreads();   // protect phi_s before next pass
    }

    const int gy = by * OT + oy, gx = bx * OT + ox0;
    float4 v4 = make_float4(o0, o1, o2, o3);
    *reinterpret_cast<float4*>(part + (size_t)g * NPIX + b * (HH * WW)
                               + gy * WW + gx) = v4;
}

__global__ __launch_bounds__(256)
void combine_kernel(const float* __restrict__ u,
                    const float* __restrict__ f,
                    const float* __restrict__ lam,
                    const float* __restrict__ part,
                    float* __restrict__ out)
{
    int i = blockIdx.x * 256 + threadIdx.x;  // 512 blocks -> NPIX
    float d = 0.f;
    #pragma unroll
    for (int g = 0; g < NG; ++g) d += part[g * NPIX + i];
    float lv = lam[0];
    float uv = u[i];
    float fv = f[i];
    out[i] = uv - d - lv * (uv - fv);
}

extern "C" void kernel_launch(void* const* d_in, const int* in_sizes, int n_in,
                              void* d_out, int out_size, void* d_ws, size_t ws_size,
                              hipStream_t stream) {
    const float* u    = (const float*)d_in[0];
    const float* f    = (const float*)d_in[1];
    const float* filt = (const float*)d_in[2];
    const float* rbfw = (const float*)d_in[3];
    const float* lam  = (const float*)d_in[4];
    float* out = (float*)d_out;
    float* part = (float*)d_ws;   // 6 * 131072 f32 partial sums (3.1 MB)
    // phi tables overlaid on d_out scratch (48*386 = 18528 floats <= 131072);
    // combine_kernel fully overwrites d_out afterwards (pattern passed in r3).
    float* tabg = (float*)d_out;

    tnrd_table<<<NC, 256, 0, stream>>>(rbfw, tabg);
    tnrd_main<<<dim3(8, 8, 2 * NG), 256, 0, stream>>>(u, filt, tabg, part);
    combine_kernel<<<512, 256, 0, stream>>>(u, f, lam, part, out);
}